// Round 3
// baseline (195.678 us; speedup 1.0000x reference)
//
#include <hip/hip_runtime.h>
#include <stdint.h>

typedef float f32x4 __attribute__((ext_vector_type(4)));
typedef __bf16 bf16x8 __attribute__((ext_vector_type(8)));
typedef int i32x4 __attribute__((ext_vector_type(4)));
typedef unsigned short u16;
typedef unsigned int u32;

#define N_NODES 8192
#define F_IN 512
#define F_OUT 128
#define LRA 0.2f

__device__ __forceinline__ u16 f32_to_bf16(float f) {
  union { float f; u32 u; } v; v.f = f;
  u32 u = v.u;
  u += 0x7fffu + ((u >> 16) & 1u);   // round-to-nearest-even
  return (u16)(u >> 16);
}
__device__ __forceinline__ float dot4(f32x4 a, f32x4 b) {
  return a[0] * b[0] + a[1] * b[1] + a[2] * b[2] + a[3] * b[3];
}

// ---------------------------------------------------------------------------
// prep_k: WT[d][k] = bf16(W[k][d])  (128 x 512), and wa = [W@a1 ; W@a2] fp32.
// ---------------------------------------------------------------------------
__global__ __launch_bounds__(256) void prep_k(
    const float* __restrict__ W, const float* __restrict__ av,
    u16* __restrict__ WT, float* __restrict__ wa) {
  __shared__ u16 Ts[F_OUT][40];
  const int t = threadIdx.x, kc = (int)blockIdx.x * 32;
  {
    const int k = t >> 3, dof = (t & 7) * 16;
#pragma unroll
    for (int q = 0; q < 4; ++q) {
      f32x4 v = *(const f32x4*)&W[(size_t)(kc + k) * F_OUT + dof + q * 4];
#pragma unroll
      for (int e = 0; e < 4; ++e) Ts[dof + q * 4 + e][k] = f32_to_bf16(v[e]);
    }
  }
  __syncthreads();
  {
    const int d = t >> 1, kh = (t & 1) * 16;
    uint4 o0 = *(uint4*)&Ts[d][kh];
    uint4 o1 = *(uint4*)&Ts[d][kh + 8];
    *(uint4*)&WT[(size_t)d * F_IN + kc + kh] = o0;
    *(uint4*)&WT[(size_t)d * F_IN + kc + kh + 8] = o1;
  }
  {
    const int kl = t >> 3, l8 = t & 7;
    const float* wrow = &W[(size_t)(kc + kl) * F_OUT];
    float s1 = 0.f, s2 = 0.f;
#pragma unroll
    for (int q = 0; q < 2; ++q) {
      int dd = l8 * 16 + q * 8;
      f32x4 w0 = *(const f32x4*)&wrow[dd];
      f32x4 w1 = *(const f32x4*)&wrow[dd + 4];
      s1 += dot4(w0, *(const f32x4*)&av[dd]) + dot4(w1, *(const f32x4*)&av[dd + 4]);
      s2 += dot4(w0, *(const f32x4*)&av[F_OUT + dd]) + dot4(w1, *(const f32x4*)&av[F_OUT + dd + 4]);
    }
#pragma unroll
    for (int m = 1; m <= 4; m <<= 1) {
      s1 += __shfl_xor(s1, m, 64);
      s2 += __shfl_xor(s2, m, 64);
    }
    if (l8 == 0) { wa[kc + kl] = s1; wa[F_IN + kc + kl] = s2; }
  }
}

// ---------------------------------------------------------------------------
// gemm_wh: WhT[d][i] = bf16( (h @ W)[i][d] ) via 16x16x32 bf16 MFMA.
// Wh1/Wh2 computed EXACTLY in fp32 as h @ (W@a) fused into A-staging.
// ---------------------------------------------------------------------------
__global__ __launch_bounds__(256) void gemm_wh(
    const float* __restrict__ h, const u16* __restrict__ WT,
    const float* __restrict__ wa,
    u16* __restrict__ WhT, float* __restrict__ Wh1, float* __restrict__ Wh2) {
  __shared__ u16 Ab[2][32][80];
  __shared__ u16 Bs[2][F_OUT][80];
  const int t = threadIdx.x;
  const int i0 = (int)blockIdx.x * 32;
  const int w = t >> 6, l = t & 63, r = l & 15, oct = l >> 4;
  const int mrow = (w & 1) * 16, ncol = (w >> 1) * 64;
  const int ar = t >> 3, ak = (t & 7) * 8;
  const int br = t >> 1, bk = (t & 1) * 32;

  const float* hrow = &h[(size_t)(i0 + ar) * F_IN + ak];
  const u16* wtrow = &WT[(size_t)br * F_IN + bk];
  const float* wap = &wa[ak];
  const float* wbp = &wa[F_IN + ak];

  f32x4 acc[4];
#pragma unroll
  for (int nf = 0; nf < 4; ++nf) acc[nf] = (f32x4){0.f, 0.f, 0.f, 0.f};
  float s1 = 0.f, s2 = 0.f;

  f32x4 ra0, ra1;
  uint4 rb[4];

#define STORE_A(B)                                                        \
  { u32 p0 = f32_to_bf16(ra0[0]) | ((u32)f32_to_bf16(ra0[1]) << 16);      \
    u32 p1 = f32_to_bf16(ra0[2]) | ((u32)f32_to_bf16(ra0[3]) << 16);      \
    u32 p2 = f32_to_bf16(ra1[0]) | ((u32)f32_to_bf16(ra1[1]) << 16);      \
    u32 p3 = f32_to_bf16(ra1[2]) | ((u32)f32_to_bf16(ra1[3]) << 16);      \
    uint4 v; v.x = p0; v.y = p1; v.z = p2; v.w = p3;                      \
    *(uint4*)&Ab[B][ar][ak] = v; }
#define STORE_B(B)                                                        \
  { *(uint4*)&Bs[B][br][bk + 0]  = rb[0];                                 \
    *(uint4*)&Bs[B][br][bk + 8]  = rb[1];                                 \
    *(uint4*)&Bs[B][br][bk + 16] = rb[2];                                 \
    *(uint4*)&Bs[B][br][bk + 24] = rb[3]; }

  ra0 = *(const f32x4*)&hrow[0];
  ra1 = *(const f32x4*)&hrow[4];
#pragma unroll
  for (int j = 0; j < 4; ++j) rb[j] = *(const uint4*)&wtrow[j * 8];
  s1 += dot4(ra0, *(const f32x4*)&wap[0]) + dot4(ra1, *(const f32x4*)&wap[4]);
  s2 += dot4(ra0, *(const f32x4*)&wbp[0]) + dot4(ra1, *(const f32x4*)&wbp[4]);
  STORE_A(0); STORE_B(0);
  __syncthreads();

#pragma unroll
  for (int it = 0; it < 8; ++it) {
    const int buf = it & 1;
    if (it < 7) {
      const int kc = (it + 1) * 64;
      ra0 = *(const f32x4*)&hrow[kc];
      ra1 = *(const f32x4*)&hrow[kc + 4];
#pragma unroll
      for (int j = 0; j < 4; ++j) rb[j] = *(const uint4*)&wtrow[kc + j * 8];
      s1 += dot4(ra0, *(const f32x4*)&wap[kc]) + dot4(ra1, *(const f32x4*)&wap[kc + 4]);
      s2 += dot4(ra0, *(const f32x4*)&wbp[kc]) + dot4(ra1, *(const f32x4*)&wbp[kc + 4]);
    }
#pragma unroll
    for (int ks = 0; ks < 2; ++ks) {
      bf16x8 af = *(bf16x8*)&Ab[buf][mrow + r][ks * 32 + oct * 8];
#pragma unroll
      for (int nf = 0; nf < 4; ++nf) {
        bf16x8 bfv = *(bf16x8*)&Bs[buf][ncol + nf * 16 + r][ks * 32 + oct * 8];
        acc[nf] = __builtin_amdgcn_mfma_f32_16x16x32_bf16(af, bfv, acc[nf], 0, 0, 0);
      }
    }
    if (it < 7) {
      STORE_A(buf ^ 1); STORE_B(buf ^ 1);
      __syncthreads();
    }
  }
#undef STORE_A
#undef STORE_B

#pragma unroll
  for (int m = 1; m <= 4; m <<= 1) {
    s1 += __shfl_xor(s1, m, 64);
    s2 += __shfl_xor(s2, m, 64);
  }
  if ((t & 7) == 0) { Wh1[i0 + ar] = s1; Wh2[i0 + ar] = s2; }

#pragma unroll
  for (int nf = 0; nf < 4; ++nf) {
    u32 lo = f32_to_bf16(acc[nf][0]) | ((u32)f32_to_bf16(acc[nf][1]) << 16);
    u32 hi = f32_to_bf16(acc[nf][2]) | ((u32)f32_to_bf16(acc[nf][3]) << 16);
    const int d = ncol + nf * 16 + r;
    uint2 v; v.x = lo; v.y = hi;
    *(uint2*)&WhT[(size_t)d * N_NODES + i0 + mrow + oct * 4] = v;
  }
}

// ---------------------------------------------------------------------------
// gat_main: barrier-free per-wave pipeline. Each wave owns a 16-row strip.
// A-fragments (P tile) built DIRECTLY in registers from adj loads (lane l =
// adj row l&15, cols (l>>4)*8..+7 -> exactly the 16x16x32 A-frag layout).
// No P-LDS, no __syncthreads in the hot loop. adj prefetched 1 chunk deep,
// nontemporal (don't evict WhT from L2). V-frags direct from L2-resident WhT.
// Wh2 slice staged once in LDS (broadcast reads, conflict-free).
// ---------------------------------------------------------------------------
__global__ __launch_bounds__(256, 3) void gat_main(
    const int* __restrict__ adj, const float* __restrict__ Wh1,
    const float* __restrict__ Wh2, const u16* __restrict__ WhT,
    float* __restrict__ accp, float* __restrict__ sp,
    const int js, const int jlen) {
  __shared__ float w2s[8192];
  const int t = threadIdx.x;
  const int bi = (int)blockIdx.x / js;
  const int jsi = (int)blockIdx.x % js;
  const int j0 = jsi * jlen;
  const int w = t >> 6, l = t & 63;
  const int r = l & 15, oct = l >> 4;
  const int i0w = bi * 64 + w * 16;

  for (int k = t * 4; k < jlen; k += 1024)
    *(f32x4*)&w2s[k] = *(const f32x4*)&Wh2[j0 + k];
  const float cI = Wh1[i0w + r];
  __syncthreads();

  const i32x4* arow = (const i32x4*)&adj[(size_t)(i0w + r) * N_NODES + j0 + oct * 8];
  const u16* vbase = &WhT[(size_t)r * N_NODES + j0 + oct * 8];

  f32x4 acc[8];
#pragma unroll
  for (int d = 0; d < 8; ++d) acc[d] = (f32x4){0.f, 0.f, 0.f, 0.f};
  float sAcc = 0.f;

  // adj prefetch: pa[q] = int4 for (ks = q>>1, half = q&1)
  i32x4 pa[4];
#pragma unroll
  for (int q = 0; q < 4; ++q)
    pa[q] = __builtin_nontemporal_load(&arow[(q >> 1) * 8 + (q & 1)]);

  for (int ch = 0; ch < jlen; ch += 64) {
    i32x4 ca[4];
#pragma unroll
    for (int q = 0; q < 4; ++q) ca[q] = pa[q];
    if (ch + 64 < jlen) {
      const i32x4* an = arow + ((ch + 64) >> 2);
#pragma unroll
      for (int q = 0; q < 4; ++q)
        pa[q] = __builtin_nontemporal_load(&an[(q >> 1) * 8 + (q & 1)]);
    }

#pragma unroll
    for (int ks = 0; ks < 2; ++ks) {
      // issue V-frag loads first (L2), latency hides under the exp block
      const u16* vp = vbase + ch + ks * 32;
      bf16x8 bv[8];
#pragma unroll
      for (int df = 0; df < 8; ++df)
        bv[df] = *(const bf16x8*)(vp + (size_t)df * 16 * N_NODES);

      // build A-frag in registers: P = adj ? exp(lrelu(cI + w2)) : 0
      f32x4 w20 = *(const f32x4*)&w2s[ch + ks * 32 + oct * 8];
      f32x4 w21 = *(const f32x4*)&w2s[ch + ks * 32 + oct * 8 + 4];
      union { u32 u[4]; bf16x8 v; } afu;
      float ps = 0.f;
#pragma unroll
      for (int e2 = 0; e2 < 4; ++e2) {
        float wa2 = (e2 < 2) ? w20[2 * e2] : w21[2 * e2 - 4];
        float wb2 = (e2 < 2) ? w20[2 * e2 + 1] : w21[2 * e2 - 3];
        int a0 = ca[ks * 2 + (e2 >> 1)][(e2 & 1) * 2];
        int a1 = ca[ks * 2 + (e2 >> 1)][(e2 & 1) * 2 + 1];
        float x0 = cI + wa2; x0 = fmaxf(x0, LRA * x0);
        float x1 = cI + wb2; x1 = fmaxf(x1, LRA * x1);
        float p0 = a0 ? __expf(x0) : 0.f;
        float p1 = a1 ? __expf(x1) : 0.f;
        ps += p0 + p1;
        afu.u[e2] = (u32)f32_to_bf16(p0) | ((u32)f32_to_bf16(p1) << 16);
      }
      sAcc += ps;

#pragma unroll
      for (int df = 0; df < 8; ++df)
        acc[df] = __builtin_amdgcn_mfma_f32_16x16x32_bf16(afu.v, bv[df], acc[df], 0, 0, 0);
    }
  }

  // denominator: lanes {l, l^16, l^32, l^48} share row r
  float s = sAcc;
  s += __shfl_xor(s, 16, 64);
  s += __shfl_xor(s, 32, 64);
  if (l < 16) sp[(size_t)jsi * N_NODES + i0w + l] = s;

  // numerator partials: C frag col=lane&15, row=(lane>>4)*4+reg
  float* ap = &accp[((size_t)jsi * N_NODES + i0w + oct * 4) * F_OUT + r];
#pragma unroll
  for (int df = 0; df < 8; ++df)
#pragma unroll
    for (int rr = 0; rr < 4; ++rr)
      __builtin_nontemporal_store(acc[df][rr], ap + (size_t)rr * F_OUT + df * 16);
}

// ---------------------------------------------------------------------------
// finalize: reduce j-split partials (f32x4 vectorized), divide, ELU.
// ---------------------------------------------------------------------------
__global__ __launch_bounds__(256) void finalize_k(
    const float* __restrict__ accp, const float* __restrict__ sp,
    float* __restrict__ out, const int js) {
  const int vidx = (int)blockIdx.x * 256 + threadIdx.x;   // f32x4 index
  const int i = vidx >> 5;                                 // node row
  f32x4 num = (f32x4){0.f, 0.f, 0.f, 0.f};
  float den = 0.f;
  for (int s = 0; s < js; ++s) {
    num += __builtin_nontemporal_load((const f32x4*)accp + (size_t)s * (N_NODES * F_OUT / 4) + vidx);
    den += sp[(size_t)s * N_NODES + i];
  }
  f32x4 o;
#pragma unroll
  for (int c = 0; c < 4; ++c) {
    float x = num[c] / den;
    o[c] = x > 0.f ? x : expm1f(x);
  }
  *((f32x4*)out + vidx) = o;
}

// ---------------------------------------------------------------------------
extern "C" void kernel_launch(void* const* d_in, const int* in_sizes, int n_in,
                              void* d_out, int out_size, void* d_ws, size_t ws_size,
                              hipStream_t stream) {
  const float* h = (const float*)d_in[0];
  const int* adj = (const int*)d_in[1];
  const float* W = (const float*)d_in[2];
  const float* av = (const float*)d_in[3];
  float* out = (float*)d_out;
  char* ws = (char*)d_ws;

  u16* WT = (u16*)ws;                                   // 128 KB
  float* wa = (float*)(ws + (256ull << 10));            // 4 KB
  u16* WhT = (u16*)(ws + (512ull << 10));               // 2 MB
  float* Wh1 = (float*)(ws + (512ull << 10) + (2ull << 20));
  float* Wh2 = (float*)(ws + (512ull << 10) + (2ull << 20) + (32ull << 10));
  float* sp = (float*)(ws + (512ull << 10) + (2ull << 20) + (64ull << 10));
  float* accp = (float*)(ws + (512ull << 10) + (2ull << 20) + (320ull << 10));
  const size_t base = (512ull << 10) + (2ull << 20) + (320ull << 10);

  int js = 8;
  while (js > 1 && base + (size_t)js * N_NODES * F_OUT * 4 > ws_size) js >>= 1;
  const int jlen = N_NODES / js;

  prep_k<<<16, 256, 0, stream>>>(W, av, WT, wa);
  gemm_wh<<<N_NODES / 32, 256, 0, stream>>>(h, WT, wa, WhT, Wh1, Wh2);
  gat_main<<<(N_NODES / 64) * js, 256, 0, stream>>>(adj, Wh1, Wh2, WhT, accp, sp, js, jlen);
  finalize_k<<<(N_NODES * F_OUT) / 1024, 256, 0, stream>>>(accp, sp, out, js);
}